// Round 2
// baseline (396.840 us; speedup 1.0000x reference)
//
#include <hip/hip_runtime.h>
#include <hip/hip_bf16.h>
#include <math.h>

#define B_    8
#define S_    2048
#define KIN_  512
#define NIN_  4096
#define P_    2048
#define D_    1024
#define KSEL_ 256

typedef __attribute__((ext_vector_type(8))) short short8;
typedef __attribute__((ext_vector_type(4))) float f32x4;

__device__ __forceinline__ unsigned short f2bf(float f) {
    unsigned u = __float_as_uint(f);
    unsigned r = (u + 0x7fffu + ((u >> 16) & 1u)) >> 16;
    return (unsigned short)r;
}
__device__ __forceinline__ float bf2f(unsigned short h) {
    return __uint_as_float(((unsigned)h) << 16);
}
__device__ __forceinline__ float gelu_exact(float x) {
    return 0.5f * x * (1.0f + erff(x * 0.70710678118654752f));
}
__device__ __forceinline__ void gl2lds16(const void* g, void* l) {
    __builtin_amdgcn_global_load_lds(
        (const __attribute__((address_space(1))) unsigned int*)g,
        (__attribute__((address_space(3))) unsigned int*)l, 16, 0, 0);
}

// ---------------------------------------------------------------------------
// Fragment-swizzled "lo" layouts (both 16 MB, same slots as before):
//   AloF[b][kb][sb][lane][8]: element (s,k) at b*1048576 + (k>>5)*65536
//       + (s>>4)*512 + (((k>>3)&3)*16 + (s&15))*8 + (k&7)
//   GloF[b][kb][pb][lane][8]: same with p in place of s.
// A 16-row x 32-k MFMA fragment block is a contiguous 1KB chunk -> one
// coalesced global_load_dwordx4 per lane, straight into the MFMA operand.
// ---------------------------------------------------------------------------

// ---------------------------------------------------------------------------
// prep: blocks [0,1024): split A fp32 -> Ahi (row-major bf16) + AloF
//       blocks [1024,5120): gather W rows by idx (idx staged in LDS),
//       4 p-rows per block; write Ghi row-major + GloF fragment-swizzled.
// ---------------------------------------------------------------------------
__global__ __launch_bounds__(256) void prep_kernel(
        const float* __restrict__ A, const float* __restrict__ W,
        const int* __restrict__ idx,
        unsigned short* __restrict__ Ahi, unsigned short* __restrict__ AloF,
        unsigned short* __restrict__ Ghi, unsigned short* __restrict__ GloF) {
    __shared__ int ibs[KIN_];
    int id = blockIdx.x;
    int t  = threadIdx.x;
    if (id < 1024) {
        int b = id >> 7, rb = id & 127;
        int l = t & 63, wv = t >> 6;
        int lr = l & 15, quad = l >> 4;
        const float* src = A + ((size_t)(b * S_ + rb * 16 + lr)) * KIN_ + quad * 8;
        unsigned short* dh = Ahi + ((size_t)(b * S_ + rb * 16 + lr)) * KIN_ + quad * 8;
        unsigned short* dl = AloF + (size_t)b * 1048576 + (size_t)rb * 512 + (size_t)l * 8;
        for (int kb = wv; kb < 16; kb += 4) {
            float4 v0 = *(const float4*)(src + kb * 32);
            float4 v1 = *(const float4*)(src + kb * 32 + 4);
            float vv[8] = {v0.x, v0.y, v0.z, v0.w, v1.x, v1.y, v1.z, v1.w};
            short8 h8, l8;
#pragma unroll
            for (int jj = 0; jj < 8; jj++) {
                unsigned short h = f2bf(vv[jj]);
                h8[jj] = (short)h;
                l8[jj] = (short)f2bf(vv[jj] - bf2f(h));
            }
            *(short8*)(dh + kb * 32) = h8;
            *(short8*)(dl + (size_t)kb * 65536) = l8;
        }
    } else {
        int g = id - 1024;              // 0..4095 ; 512 blocks per batch
        int b = g >> 9;
        ibs[t]       = idx[b * KIN_ + t];
        ibs[t + 256] = idx[b * KIN_ + t + 256];
        __syncthreads();
        int wv = t >> 6, tt = t & 63;
        int p  = (g * 4 + wv) & 2047;
        const float* wrow = W + (size_t)p * NIN_;
        size_t o = ((size_t)b * P_ + p) * KIN_;
        unsigned short* gf = GloF + (size_t)b * 1048576 + (size_t)(tt >> 2) * 65536
                           + (size_t)(p >> 4) * 512
                           + (size_t)((tt & 3) * 16 + (p & 15)) * 8;
        short8 h8, l8;
#pragma unroll
        for (int e = 0; e < 8; e++) {
            float v = wrow[ibs[tt * 8 + e]];
            unsigned short h = f2bf(v);
            h8[e] = (short)h;
            l8[e] = (short)f2bf(v - bf2f(h));
        }
        *(short8*)(Ghi + o + tt * 8) = h8;
        *(short8*)gf = l8;
    }
}

// ---------------------------------------------------------------------------
// gemm1_score: x = A*G^T (3-term split bf16 MFMA), scores += sum_s gelu(x).
// Optionally (STORE_C) writes bf16 gelu(x) to C [b][s][p].
// 128x128 tile, BK=32. LDS stages only Ahi/Ghi (2 x 16KB dbuf -> 32KB);
// AloF and GloF fragments loaded direct global->reg (coalesced, L2-hot).
// __launch_bounds__(256,4): VGPR<=128 -> 4 blocks/CU (16 waves/CU).
// Source+read XOR swizzle on staged tiles kills ds_read_b128 conflicts.
// vmcnt(12) = 8 direct loads + 4 next-buffer staging in flight.
// Block swizzle: 4x4 (p,s)-tile clusters pinned to one XCD.
// ---------------------------------------------------------------------------
template <bool STORE_C>
__global__ __launch_bounds__(256, 4) void gemm1_score(
        const unsigned short* __restrict__ Ahi, const unsigned short* __restrict__ AloF,
        const unsigned short* __restrict__ Ghi, const unsigned short* __restrict__ GloF,
        float* __restrict__ scores, unsigned short* __restrict__ C) {
    __shared__ __align__(16) unsigned short lds[16384];  // 2 x 16KB buffers

    // --- XCD cluster swizzle ---
    int d    = blockIdx.x;             // 0..2047
    int xcd  = d & 7;
    int slot = d >> 3;                 // 0..255
    int c    = (slot >> 4) * 8 + xcd;  // cluster 0..127
    int j    = slot & 15;              // position in 4x4 cluster
    int b    = c >> 4;
    int rc   = c & 15;
    int p0   = ((rc & 3) * 4 + (j & 3)) * 128;
    int s0   = ((rc >> 2) * 4 + (j >> 2)) * 128;

    const int t  = threadIdx.x;
    const int w = t >> 6, l = t & 63;
    const int wm = w & 1, wn = w >> 1;
    const int lr = l & 15, quad = l >> 4;

    const int srow = t >> 2;
    const int koff = ((t & 3) ^ ((t >> 3) & 3)) * 8;   // source-side swizzle
    const size_t baseA = ((size_t)(b * S_ + s0)) * KIN_;
    const size_t baseG = ((size_t)(b * P_ + p0)) * KIN_;
    const unsigned short* pA0 = Ahi + baseA + (size_t)srow * KIN_ + koff;
    const unsigned short* pA1 = pA0 + (size_t)64 * KIN_;
    const unsigned short* pG0 = Ghi + baseG + (size_t)srow * KIN_ + koff;
    const unsigned short* pG1 = pG0 + (size_t)64 * KIN_;
    const unsigned short* alB = AloF + (size_t)b * 1048576
                              + (size_t)((s0 >> 4) + wm * 4) * 512 + (size_t)l * 8;
    const unsigned short* glB = GloF + (size_t)b * 1048576
                              + (size_t)((p0 >> 4) + wn * 4) * 512 + (size_t)l * 8;
    char* lb = (char*)lds + w * 1024;

    int ra[4], rg[4];
#pragma unroll
    for (int i = 0; i < 4; i++) {
        int rowa = wm * 64 + i * 16 + lr;
        int rowg = wn * 64 + i * 16 + lr;
        ra[i] = rowa * 32 + (quad ^ ((rowa >> 1) & 3)) * 8;
        rg[i] = rowg * 32 + (quad ^ ((rowg >> 1) & 3)) * 8;
    }

    f32x4 acc[4][4];
#pragma unroll
    for (int i = 0; i < 4; i++)
#pragma unroll
        for (int jj = 0; jj < 4; jj++) acc[i][jj] = (f32x4){0.f, 0.f, 0.f, 0.f};

    auto issue = [&](int k0, int buf) {
        char* dst = lb + buf * 16384;
        gl2lds16(pA0 + k0, dst + 0);
        gl2lds16(pA1 + k0, dst + 4096);
        gl2lds16(pG0 + k0, dst + 8192);
        gl2lds16(pG1 + k0, dst + 12288);
    };

    issue(0, 0);
    for (int it = 0; it < KIN_ / 32; ++it) {
        // lo-operand fragments for this K-step, direct from global (1KB/frag)
        short8 alc[4], glc[4];
#pragma unroll
        for (int i = 0; i < 4; i++) {
            alc[i] = *(const short8*)(alB + (size_t)it * 65536 + i * 512);
            glc[i] = *(const short8*)(glB + (size_t)it * 65536 + i * 512);
        }
        if (it + 1 < KIN_ / 32) {
            issue((it + 1) * 32, (it + 1) & 1);
            // outstanding: stage(it)[4] + alc/glc[8] + stage(it+1)[4] = 16
            asm volatile("s_waitcnt vmcnt(12)\n\ts_barrier" ::: "memory");
        } else {
            asm volatile("s_waitcnt vmcnt(8)\n\ts_barrier" ::: "memory");
        }
        const unsigned short* Lb = lds + (it & 1) * 8192;

        short8 gh[4];
#pragma unroll
        for (int i = 0; i < 4; i++) gh[i] = *(const short8*)(Lb + 4096 + rg[i]);
#pragma unroll
        for (int mt = 0; mt < 4; mt++) {
            short8 ah = *(const short8*)(Lb + ra[mt]);
#pragma unroll
            for (int nt = 0; nt < 4; nt++) {
                acc[mt][nt] = __builtin_amdgcn_mfma_f32_16x16x32_bf16(ah,      gh[nt],  acc[mt][nt], 0, 0, 0);
                acc[mt][nt] = __builtin_amdgcn_mfma_f32_16x16x32_bf16(ah,      glc[nt], acc[mt][nt], 0, 0, 0);
                acc[mt][nt] = __builtin_amdgcn_mfma_f32_16x16x32_bf16(alc[mt], gh[nt],  acc[mt][nt], 0, 0, 0);
            }
        }
        asm volatile("s_barrier" ::: "memory");
    }

    // Epilogue: gelu, per-column score sums, optional bf16 C tile store
    float colsum[4] = {0.f, 0.f, 0.f, 0.f};
#pragma unroll
    for (int mt = 0; mt < 4; mt++)
#pragma unroll
        for (int nt = 0; nt < 4; nt++)
#pragma unroll
            for (int r = 0; r < 4; r++) {
                float g = gelu_exact(acc[mt][nt][r]);
                colsum[nt] += g;
                acc[mt][nt][r] = g;
            }
#pragma unroll
    for (int nt = 0; nt < 4; nt++) {
        colsum[nt] += __shfl_xor(colsum[nt], 16);
        colsum[nt] += __shfl_xor(colsum[nt], 32);
    }
    if (quad == 0) {
#pragma unroll
        for (int nt = 0; nt < 4; nt++)
            atomicAdd(&scores[b * P_ + p0 + wn * 64 + nt * 16 + lr], colsum[nt]);
    }

    if (STORE_C) {
#pragma unroll
        for (int mt = 0; mt < 4; mt++)
#pragma unroll
            for (int nt = 0; nt < 4; nt++)
#pragma unroll
                for (int r = 0; r < 4; r++) {
                    int row = wm * 64 + mt * 16 + quad * 4 + r;
                    int col = wn * 64 + nt * 16 + lr;
                    lds[row * 128 + col] = f2bf(acc[mt][nt][r]);
                }
        __syncthreads();
        for (int i = t; i < 2048; i += 256) {
            int row = i >> 4, ch = i & 15;
            uint4 v = *(const uint4*)(lds + row * 128 + ch * 8);
            *(uint4*)(C + ((size_t)(b * S_ + s0 + row)) * P_ + p0 + ch * 8) = v;
        }
    }
}

// ---------------------------------------------------------------------------
// top-256 of 2048 scores per batch (bitonic, desc, tie: low idx)
// ---------------------------------------------------------------------------
__global__ __launch_bounds__(1024) void topk_kernel(const float* __restrict__ scores,
                                                    int* __restrict__ pidx) {
    __shared__ float v[2048];
    __shared__ int   ix[2048];
    int b = blockIdx.x;
    int t = threadIdx.x;
    for (int i = t; i < 2048; i += 1024) { v[i] = scores[b * 2048 + i]; ix[i] = i; }
    __syncthreads();
    for (int k = 2; k <= 2048; k <<= 1) {
        for (int j = k >> 1; j > 0; j >>= 1) {
            for (int i = t; i < 2048; i += 1024) {
                int o = i ^ j;
                if (o > i) {
                    bool desc = ((i & k) == 0);
                    float va = v[i], vb = v[o];
                    int ia = ix[i], ib = ix[o];
                    bool b_first = (vb > va) || (vb == va && ib < ia);
                    if (desc == b_first) { v[i] = vb; v[o] = va; ix[i] = ib; ix[o] = ia; }
                }
            }
            __syncthreads();
        }
    }
    if (t < KSEL_) pidx[b * KSEL_ + t] = ix[t];
}

// ---------------------------------------------------------------------------
// gathers: id in [0,2048): selact[b][s][t] = C[b][s][pidx[b][t]]
//          id in [2048,2560): PselT[b][d][k] = bf16(proj[pidx[b][k]][d])
// base offsets blockIdx so the small-ws path can launch only the proj part.
// ---------------------------------------------------------------------------
__global__ __launch_bounds__(256) void gathers_kernel(
        const unsigned short* __restrict__ C, const float* __restrict__ proj,
        const int* __restrict__ pidx,
        unsigned short* __restrict__ selact, unsigned short* __restrict__ PselT,
        int base) {
    __shared__ int pj[256];
    __shared__ unsigned short tile[64][65];
    int id = blockIdx.x + base, t = threadIdx.x;
    if (id < 2048) {
        int b = id >> 8;
        pj[t] = pidx[b * KSEL_ + t];
        __syncthreads();
        size_t r0 = (size_t)b * S_ + (id & 255) * 8;
#pragma unroll
        for (int r = 0; r < 8; ++r) {
            size_t row = r0 + r;
            selact[row * KSEL_ + t] = C[row * P_ + pj[t]];
        }
    } else {
        int g = id - 2048;
        int d0 = (g & 15) * 64, k0 = ((g >> 4) & 3) * 64, b = g >> 6;
        int tr = t >> 6;     // 0..3
        int tc = t & 63;
#pragma unroll
        for (int r = 0; r < 16; r++) {
            int kk = r * 4 + tr;
            int prow = pidx[b * KSEL_ + k0 + kk];
            tile[kk][tc] = f2bf(proj[(size_t)prow * D_ + d0 + tc]);
        }
        __syncthreads();
#pragma unroll
        for (int r = 0; r < 16; r++) {
            int dd = r * 4 + tr;
            PselT[((size_t)(b * D_ + d0 + dd)) * KSEL_ + k0 + tc] = tile[tc][dd];
        }
    }
}

// ---------------------------------------------------------------------------
// gemm1b (fallback when ws too small): recompute selected 256 columns.
// Ahi/Ghi staged in LDS (single buffer); AloF direct; GloF per-lane direct
// (fragment k-octets are p-independent contiguous 16B chunks).
// ---------------------------------------------------------------------------
__global__ __launch_bounds__(256) void gemm1b_selact(
        const unsigned short* __restrict__ Ahi, const unsigned short* __restrict__ AloF,
        const unsigned short* __restrict__ Ghi, const unsigned short* __restrict__ GloF,
        const int* __restrict__ pidx, unsigned short* __restrict__ selact) {
    __shared__ __align__(16) unsigned short lds[16384];

    const int t  = threadIdx.x;
    const int b  = blockIdx.z;
    const int s0 = blockIdx.y * 128;
    const int n0 = blockIdx.x * 128;
    const int w = t >> 6, l = t & 63;
    const int wm = w & 1, wn = w >> 1;
    const int lr = l & 15, quad = l >> 4;

    const int srow = t >> 2;
    const int koff = ((t & 3) ^ ((t >> 3) & 3)) * 8;
    const size_t baseA = ((size_t)(b * S_ + s0)) * KIN_;
    const size_t offA0 = baseA + (size_t)srow * KIN_ + koff;
    const size_t offA1 = offA0 + (size_t)64 * KIN_;
    const int prow0 = pidx[b * KSEL_ + n0 + srow];
    const int prow1 = pidx[b * KSEL_ + n0 + 64 + srow];
    const size_t offG0 = ((size_t)(b * P_ + prow0)) * KIN_ + koff;
    const size_t offG1 = ((size_t)(b * P_ + prow1)) * KIN_ + koff;
    const unsigned short* alB = AloF + (size_t)b * 1048576
                              + (size_t)((s0 >> 4) + wm * 4) * 512 + (size_t)l * 8;
    const unsigned short* glb = GloF + (size_t)b * 1048576;
    size_t gloff[4];
#pragma unroll
    for (int i = 0; i < 4; i++) {
        int pp = pidx[b * KSEL_ + n0 + wn * 64 + i * 16 + lr];
        gloff[i] = (size_t)(pp >> 4) * 512 + (size_t)(quad * 16 + (pp & 15)) * 8;
    }
    char* lb = (char*)lds + w * 1024;

    int ra[4], rg[4];
#pragma unroll
    for (int i = 0; i < 4; i++) {
        int rowa = wm * 64 + i * 16 + lr;
        int rowg = wn * 64 + i * 16 + lr;
        ra[i] = rowa * 32 + (quad ^ ((rowa >> 1) & 3)) * 8;
        rg[i] = rowg * 32 + (quad ^ ((rowg >> 1) & 3)) * 8;
    }

    f32x4 acc[4][4];
#pragma unroll
    for (int i = 0; i < 4; i++)
#pragma unroll
        for (int jj = 0; jj < 4; jj++) acc[i][jj] = (f32x4){0.f, 0.f, 0.f, 0.f};

    for (int k0 = 0; k0 < KIN_; k0 += 32) {
        int kb = k0 >> 5;
        gl2lds16(Ahi + offA0 + k0, lb + 0);
        gl2lds16(Ahi + offA1 + k0, lb + 4096);
        gl2lds16(Ghi + offG0 + k0, lb + 8192);
        gl2lds16(Ghi + offG1 + k0, lb + 12288);
        short8 alc[4], glc[4];
#pragma unroll
        for (int i = 0; i < 4; i++) {
            alc[i] = *(const short8*)(alB + (size_t)kb * 65536 + i * 512);
            glc[i] = *(const short8*)(glb + (size_t)kb * 65536 + gloff[i]);
        }
        __syncthreads();

        short8 gh[4];
#pragma unroll
        for (int i = 0; i < 4; i++) gh[i] = *(const short8*)(lds + 4096 + rg[i]);
#pragma unroll
        for (int mt = 0; mt < 4; mt++) {
            short8 ah = *(const short8*)(lds + ra[mt]);
#pragma unroll
            for (int nt = 0; nt < 4; nt++) {
                acc[mt][nt] = __builtin_amdgcn_mfma_f32_16x16x32_bf16(ah,      gh[nt],  acc[mt][nt], 0, 0, 0);
                acc[mt][nt] = __builtin_amdgcn_mfma_f32_16x16x32_bf16(ah,      glc[nt], acc[mt][nt], 0, 0, 0);
                acc[mt][nt] = __builtin_amdgcn_mfma_f32_16x16x32_bf16(alc[mt], gh[nt],  acc[mt][nt], 0, 0, 0);
            }
        }
        __syncthreads();
    }

#pragma unroll
    for (int mt = 0; mt < 4; mt++)
#pragma unroll
        for (int nt = 0; nt < 4; nt++)
#pragma unroll
            for (int r = 0; r < 4; r++) {
                int row = wm * 64 + mt * 16 + quad * 4 + r;
                int col = wn * 64 + nt * 16 + lr;
                lds[row * 128 + col] = f2bf(gelu_exact(acc[mt][nt][r]));
            }
    __syncthreads();
    for (int i = t; i < 2048; i += 256) {
        int row = i >> 4, ch = i & 15;
        uint4 v = *(const uint4*)(lds + row * 128 + ch * 8);
        *(uint4*)(selact + ((size_t)(b * S_ + s0 + row)) * KSEL_ + n0 + ch * 8) = v;
    }
}

// ---------------------------------------------------------------------------
// gemm2: out[b][s][d] = sum_k selact[b][s][k] * PselT[b][d][k]  (bf16 MFMA)
// dbuf LDS + raw vmcnt(4)/s_barrier pipeline; XOR source+read swizzle.
// ---------------------------------------------------------------------------
__global__ __launch_bounds__(256, 4) void gemm2_mfma(
        const unsigned short* __restrict__ selact,
        const unsigned short* __restrict__ PselT,
        float* __restrict__ out) {
    __shared__ __align__(16) unsigned short lds[16384];  // 2 x 16KB buffers

    const int t  = threadIdx.x;
    const int b  = blockIdx.z;
    const int s0 = blockIdx.y * 128;
    const int d0 = blockIdx.x * 128;
    const int w = t >> 6, l = t & 63;
    const int wm = w & 1, wn = w >> 1;
    const int lr = l & 15, quad = l >> 4;

    const int srow = t >> 2;
    const int koff = ((t & 3) ^ ((t >> 3) & 3)) * 8;
    const unsigned short* pA0 = selact + ((size_t)(b * S_ + s0 + srow)) * KSEL_ + koff;
    const unsigned short* pA1 = pA0 + (size_t)64 * KSEL_;
    const unsigned short* pB0 = PselT + ((size_t)(b * D_ + d0 + srow)) * KSEL_ + koff;
    const unsigned short* pB1 = pB0 + (size_t)64 * KSEL_;
    char* lb = (char*)lds + w * 1024;

    int ra[4], rg[4];
#pragma unroll
    for (int i = 0; i < 4; i++) {
        int rowa = wm * 64 + i * 16 + lr;
        int rowg = wn * 64 + i * 16 + lr;
        ra[i] = rowa * 32 + (quad ^ ((rowa >> 1) & 3)) * 8;
        rg[i] = rowg * 32 + (quad ^ ((rowg >> 1) & 3)) * 8;
    }

    f32x4 acc[4][4];
#pragma unroll
    for (int i = 0; i < 4; i++)
#pragma unroll
        for (int jj = 0; jj < 4; jj++) acc[i][jj] = (f32x4){0.f, 0.f, 0.f, 0.f};

    auto issue = [&](int k0, int buf) {
        char* dst = lb + buf * 16384;
        gl2lds16(pA0 + k0, dst + 0);
        gl2lds16(pA1 + k0, dst + 4096);
        gl2lds16(pB0 + k0, dst + 8192);
        gl2lds16(pB1 + k0, dst + 12288);
    };

    issue(0, 0);
    for (int it = 0; it < KSEL_ / 32; ++it) {
        if (it + 1 < KSEL_ / 32) {
            issue((it + 1) * 32, (it + 1) & 1);
            asm volatile("s_waitcnt vmcnt(4)\n\ts_barrier" ::: "memory");
        } else {
            asm volatile("s_waitcnt vmcnt(0)\n\ts_barrier" ::: "memory");
        }
        const unsigned short* Lb = lds + (it & 1) * 8192;

        short8 af[4], bf[4];
#pragma unroll
        for (int i = 0; i < 4; i++) {
            af[i] = *(const short8*)(Lb + ra[i]);
            bf[i] = *(const short8*)(Lb + 4096 + rg[i]);
        }
#pragma unroll
        for (int mt = 0; mt < 4; mt++)
#pragma unroll
            for (int nt = 0; nt < 4; nt++)
                acc[mt][nt] = __builtin_amdgcn_mfma_f32_16x16x32_bf16(af[mt], bf[nt], acc[mt][nt], 0, 0, 0);
        asm volatile("s_barrier" ::: "memory");
    }

#pragma unroll
    for (int mt = 0; mt < 4; mt++)
#pragma unroll
        for (int nt = 0; nt < 4; nt++)
#pragma unroll
            for (int r = 0; r < 4; r++)
                out[((size_t)(b * S_ + s0 + wm * 64 + mt * 16 + quad * 4 + r)) * D_
                    + d0 + wn * 64 + nt * 16 + lr] = acc[mt][nt][r];
}

// ---------------------------------------------------------------------------
// Workspace layout (bytes):
//   Ahi/AloF/Ghi/GloF bf16 @ 0..67108863  (4 x 16,777,216; lo's frag-swizzled)
//   scores fp32           @ 67,108,864    (65,536)
//   pidx   int            @ 67,174,400    (8,192)
//   selact bf16           @ 67,182,592    (8,388,608)
//   PselT  bf16           @ 75,571,200    (4,194,304)      -> 79,765,504 (base)
//   C      bf16 [8][2048][2048] @ 79,765,504 (67,108,864)  -> 146,874,368 (big)
// ---------------------------------------------------------------------------
extern "C" void kernel_launch(void* const* d_in, const int* in_sizes, int n_in,
                              void* d_out, int out_size, void* d_ws, size_t ws_size,
                              hipStream_t stream) {
    (void)in_sizes; (void)n_in; (void)out_size;
    const float* act  = (const float*)d_in[0];
    const int*   idx  = (const int*)d_in[1];
    const float* W    = (const float*)d_in[3];
    const float* proj = (const float*)d_in[4];
    float*       out  = (float*)d_out;

    char* ws = (char*)d_ws;
    unsigned short* Ahi    = (unsigned short*)(ws + 0);
    unsigned short* AloF   = (unsigned short*)(ws + 16777216);
    unsigned short* Ghi    = (unsigned short*)(ws + 33554432);
    unsigned short* GloF   = (unsigned short*)(ws + 50331648);
    float*          scores = (float*)(ws + 67108864);
    int*            pidx   = (int*)(ws + 67174400);
    unsigned short* selact = (unsigned short*)(ws + 67182592);
    unsigned short* PselT  = (unsigned short*)(ws + 75571200);
    unsigned short* Cbf    = (unsigned short*)(ws + 79765504);
    const bool big = ws_size >= 146874368ull;

    hipMemsetAsync(scores, 0, B_ * P_ * sizeof(float), stream);

    prep_kernel<<<dim3(1024 + (B_ * P_) / 4), 256, 0, stream>>>(act, W, idx, Ahi, AloF, Ghi, GloF);

    if (big) {
        gemm1_score<true><<<dim3(2048), 256, 0, stream>>>(Ahi, AloF, Ghi, GloF, scores, Cbf);
        topk_kernel<<<dim3(B_), 1024, 0, stream>>>(scores, pidx);
        gathers_kernel<<<dim3(2048 + 512), 256, 0, stream>>>(Cbf, proj, pidx, selact, PselT, 0);
    } else {
        gemm1_score<false><<<dim3(2048), 256, 0, stream>>>(Ahi, AloF, Ghi, GloF, scores, nullptr);
        topk_kernel<<<dim3(B_), 1024, 0, stream>>>(scores, pidx);
        gemm1b_selact<<<dim3(KSEL_ / 128, S_ / 128, B_), 256, 0, stream>>>(
            Ahi, AloF, Ghi, GloF, pidx, selact);
        gathers_kernel<<<dim3(512), 256, 0, stream>>>(Cbf, proj, pidx, selact, PselT, 2048);
    }
    gemm2_mfma<<<dim3(D_ / 128, S_ / 128, B_), 256, 0, stream>>>(selact, PselT, out);
}

// Round 4
// 356.600 us; speedup vs baseline: 1.1128x; 1.1128x over previous
//
#include <hip/hip_runtime.h>
#include <hip/hip_bf16.h>
#include <math.h>

#define B_    8
#define S_    2048
#define KIN_  512
#define NIN_  4096
#define P_    2048
#define D_    1024
#define KSEL_ 256

typedef __attribute__((ext_vector_type(8))) short short8;
typedef __attribute__((ext_vector_type(4))) float f32x4;

__device__ __forceinline__ unsigned short f2bf(float f) {
    unsigned u = __float_as_uint(f);
    unsigned r = (u + 0x7fffu + ((u >> 16) & 1u)) >> 16;
    return (unsigned short)r;
}
__device__ __forceinline__ float bf2f(unsigned short h) {
    return __uint_as_float(((unsigned)h) << 16);
}
__device__ __forceinline__ float gelu_exact(float x) {
    return 0.5f * x * (1.0f + erff(x * 0.70710678118654752f));
}
__device__ __forceinline__ void gl2lds16(const void* g, void* l) {
    __builtin_amdgcn_global_load_lds(
        (const __attribute__((address_space(1))) unsigned int*)g,
        (__attribute__((address_space(3))) unsigned int*)l, 16, 0, 0);
}

// ---------------------------------------------------------------------------
// AloF fragment-swizzled layout (16 MB):
//   AloF[b][kb][sb][lane][8]: element (s,k) at b*1048576 + (k>>5)*65536
//       + (s>>4)*512 + (((k>>3)&3)*16 + (s&15))*8 + (k&7)
// A 16-row x 32-k MFMA fragment block is a contiguous 1KB chunk -> one
// coalesced global_load_dwordx4 per lane, straight into the MFMA operand.
// Ghi/Glo stay row-major (staged via global_load_lds in gemm1).
// ---------------------------------------------------------------------------

// ---------------------------------------------------------------------------
// prep: blocks [0,1024): split A fp32 -> Ahi (row-major bf16) + AloF
//       blocks [1024,5120): gather W rows by idx (idx staged in LDS),
//       4 p-rows per block; write Ghi/Glo row-major.
// ---------------------------------------------------------------------------
__global__ __launch_bounds__(256) void prep_kernel(
        const float* __restrict__ A, const float* __restrict__ W,
        const int* __restrict__ idx,
        unsigned short* __restrict__ Ahi, unsigned short* __restrict__ AloF,
        unsigned short* __restrict__ Ghi, unsigned short* __restrict__ Glo) {
    __shared__ int ibs[KIN_];
    int id = blockIdx.x;
    int t  = threadIdx.x;
    if (id < 1024) {
        int b = id >> 7, rb = id & 127;
        int l = t & 63, wv = t >> 6;
        int lr = l & 15, quad = l >> 4;
        const float* src = A + ((size_t)(b * S_ + rb * 16 + lr)) * KIN_ + quad * 8;
        unsigned short* dh = Ahi + ((size_t)(b * S_ + rb * 16 + lr)) * KIN_ + quad * 8;
        unsigned short* dl = AloF + (size_t)b * 1048576 + (size_t)rb * 512 + (size_t)l * 8;
        for (int kb = wv; kb < 16; kb += 4) {
            float4 v0 = *(const float4*)(src + kb * 32);
            float4 v1 = *(const float4*)(src + kb * 32 + 4);
            float vv[8] = {v0.x, v0.y, v0.z, v0.w, v1.x, v1.y, v1.z, v1.w};
            short8 h8, l8;
#pragma unroll
            for (int jj = 0; jj < 8; jj++) {
                unsigned short h = f2bf(vv[jj]);
                h8[jj] = (short)h;
                l8[jj] = (short)f2bf(vv[jj] - bf2f(h));
            }
            *(short8*)(dh + kb * 32) = h8;
            *(short8*)(dl + (size_t)kb * 65536) = l8;
        }
    } else {
        int g = id - 1024;              // 0..4095 ; 512 blocks per batch
        int b = g >> 9;
        ibs[t]       = idx[b * KIN_ + t];
        ibs[t + 256] = idx[b * KIN_ + t + 256];
        __syncthreads();
        int wv = t >> 6, tt = t & 63;
        int p  = (g * 4 + wv) & 2047;
        const float* wrow = W + (size_t)p * NIN_;
        size_t o = ((size_t)b * P_ + p) * KIN_;
        short8 h8, l8;
#pragma unroll
        for (int e = 0; e < 8; e++) {
            float v = wrow[ibs[tt * 8 + e]];
            unsigned short h = f2bf(v);
            h8[e] = (short)h;
            l8[e] = (short)f2bf(v - bf2f(h));
        }
        *(short8*)(Ghi + o + tt * 8) = h8;
        *(short8*)(Glo + o + tt * 8) = l8;
    }
}

// ---------------------------------------------------------------------------
// gemm1_score: x = A*G^T (3-term split bf16 MFMA), scores += sum_s gelu(x).
// Optionally (STORE_C) writes bf16 gelu(x) to C [b][s][p].
// 128x128 tile, BK=32. LDS stages Ahi/Ghi/Glo (2 x 24KB dbuf -> 48KB,
// 3 blocks/CU with ~148 total regs); AloF fragments loaded direct
// global->reg (coalesced, L2-hot). Source+read XOR swizzle kills the
// ds_read_b128 bank conflicts; epilogue tile padded to 136-short rows.
// vmcnt(10) = 6 staging(it) drained; 4 alc + 6 staging(it+1) in flight.
// Block swizzle: 4x4 (p,s)-tile clusters pinned to one XCD.
// NOTE (R2 lesson): do NOT raise min-waves to 4 — the unified VGPR file
// gives only 64 arch VGPRs at 128 total, starving the direct-load pipeline.
// ---------------------------------------------------------------------------
template <bool STORE_C>
__global__ __launch_bounds__(256, 3) void gemm1_score(
        const unsigned short* __restrict__ Ahi, const unsigned short* __restrict__ AloF,
        const unsigned short* __restrict__ Ghi, const unsigned short* __restrict__ Glo,
        float* __restrict__ scores, unsigned short* __restrict__ C) {
    __shared__ __align__(16) unsigned short lds[24576];  // 2 x 24KB buffers

    // --- XCD cluster swizzle ---
    int d    = blockIdx.x;             // 0..2047
    int xcd  = d & 7;
    int slot = d >> 3;                 // 0..255
    int c    = (slot >> 4) * 8 + xcd;  // cluster 0..127
    int j    = slot & 15;              // position in 4x4 cluster
    int b    = c >> 4;
    int rc   = c & 15;
    int p0   = ((rc & 3) * 4 + (j & 3)) * 128;
    int s0   = ((rc >> 2) * 4 + (j >> 2)) * 128;

    const int t  = threadIdx.x;
    const int w = t >> 6, l = t & 63;
    const int wm = w & 1, wn = w >> 1;
    const int lr = l & 15, quad = l >> 4;

    const int srow = t >> 2;
    const int koff = ((t & 3) ^ ((t >> 3) & 3)) * 8;   // source-side swizzle
    const size_t baseA = ((size_t)(b * S_ + s0)) * KIN_;
    const size_t baseG = ((size_t)(b * P_ + p0)) * KIN_;
    const unsigned short* pA0 = Ahi + baseA + (size_t)srow * KIN_ + koff;
    const unsigned short* pA1 = pA0 + (size_t)64 * KIN_;
    const unsigned short* pG0 = Ghi + baseG + (size_t)srow * KIN_ + koff;
    const unsigned short* pG1 = pG0 + (size_t)64 * KIN_;
    const unsigned short* pH0 = Glo + baseG + (size_t)srow * KIN_ + koff;
    const unsigned short* pH1 = pH0 + (size_t)64 * KIN_;
    const unsigned short* alB = AloF + (size_t)b * 1048576
                              + (size_t)((s0 >> 4) + wm * 4) * 512 + (size_t)l * 8;
    char* lb = (char*)lds + w * 1024;

    int ra[4], rg[4];
#pragma unroll
    for (int i = 0; i < 4; i++) {
        int rowa = wm * 64 + i * 16 + lr;
        int rowg = wn * 64 + i * 16 + lr;
        ra[i] = rowa * 32 + (quad ^ ((rowa >> 1) & 3)) * 8;
        rg[i] = rowg * 32 + (quad ^ ((rowg >> 1) & 3)) * 8;
    }

    f32x4 acc[4][4];
#pragma unroll
    for (int i = 0; i < 4; i++)
#pragma unroll
        for (int jj = 0; jj < 4; jj++) acc[i][jj] = (f32x4){0.f, 0.f, 0.f, 0.f};

    auto issue = [&](int k0, int buf) {
        char* dst = lb + buf * 24576;
        gl2lds16(pA0 + k0, dst + 0);
        gl2lds16(pA1 + k0, dst + 4096);
        gl2lds16(pG0 + k0, dst + 8192);
        gl2lds16(pG1 + k0, dst + 12288);
        gl2lds16(pH0 + k0, dst + 16384);
        gl2lds16(pH1 + k0, dst + 20480);
    };

    issue(0, 0);
    for (int it = 0; it < KIN_ / 32; ++it) {
        // Alo fragments for this K-step, direct from global (coalesced 1KB).
        short8 alc[4];
#pragma unroll
        for (int mt = 0; mt < 4; mt++)
            alc[mt] = *(const short8*)(alB + (size_t)it * 65536 + mt * 512);
        if (it + 1 < KIN_ / 32) {
            issue((it + 1) * 32, (it + 1) & 1);
            // outstanding: staging(it)[6] + alc(it)[4] + staging(it+1)[6]
            asm volatile("s_waitcnt vmcnt(10)\n\ts_barrier" ::: "memory");
        } else {
            asm volatile("s_waitcnt vmcnt(0)\n\ts_barrier" ::: "memory");
        }
        const unsigned short* Lb = lds + (it & 1) * 12288;

        short8 gh[4], gl8[4];
#pragma unroll
        for (int i = 0; i < 4; i++) {
            gh[i]  = *(const short8*)(Lb + 4096 + rg[i]);
            gl8[i] = *(const short8*)(Lb + 8192 + rg[i]);
        }
#pragma unroll
        for (int mt = 0; mt < 4; mt++) {
            short8 ah = *(const short8*)(Lb + ra[mt]);
#pragma unroll
            for (int nt = 0; nt < 4; nt++) {
                acc[mt][nt] = __builtin_amdgcn_mfma_f32_16x16x32_bf16(ah,      gh[nt],  acc[mt][nt], 0, 0, 0);
                acc[mt][nt] = __builtin_amdgcn_mfma_f32_16x16x32_bf16(ah,      gl8[nt], acc[mt][nt], 0, 0, 0);
                acc[mt][nt] = __builtin_amdgcn_mfma_f32_16x16x32_bf16(alc[mt], gh[nt],  acc[mt][nt], 0, 0, 0);
            }
        }
        asm volatile("s_barrier" ::: "memory");
    }

    // Epilogue: gelu, per-column score sums, optional bf16 C tile store
    float colsum[4] = {0.f, 0.f, 0.f, 0.f};
#pragma unroll
    for (int mt = 0; mt < 4; mt++)
#pragma unroll
        for (int nt = 0; nt < 4; nt++)
#pragma unroll
            for (int r = 0; r < 4; r++) {
                float g = gelu_exact(acc[mt][nt][r]);
                colsum[nt] += g;
                acc[mt][nt][r] = g;
            }
#pragma unroll
    for (int nt = 0; nt < 4; nt++) {
        colsum[nt] += __shfl_xor(colsum[nt], 16);
        colsum[nt] += __shfl_xor(colsum[nt], 32);
    }
    if (quad == 0) {
#pragma unroll
        for (int nt = 0; nt < 4; nt++)
            atomicAdd(&scores[b * P_ + p0 + wn * 64 + nt * 16 + lr], colsum[nt]);
    }

    if (STORE_C) {
        // padded tile: 136-short rows (272B, 16B-aligned) -> banks spread
#pragma unroll
        for (int mt = 0; mt < 4; mt++)
#pragma unroll
            for (int nt = 0; nt < 4; nt++)
#pragma unroll
                for (int r = 0; r < 4; r++) {
                    int row = wm * 64 + mt * 16 + quad * 4 + r;
                    int col = wn * 64 + nt * 16 + lr;
                    lds[row * 136 + col] = f2bf(acc[mt][nt][r]);
                }
        __syncthreads();
        for (int i = t; i < 2048; i += 256) {
            int row = i >> 4, ch = i & 15;
            uint4 v = *(const uint4*)(lds + row * 136 + ch * 8);
            *(uint4*)(C + ((size_t)(b * S_ + s0 + row)) * P_ + p0 + ch * 8) = v;
        }
    }
}

// ---------------------------------------------------------------------------
// top-256 of 2048 scores per batch (bitonic, desc, tie: low idx)
// ---------------------------------------------------------------------------
__global__ __launch_bounds__(1024) void topk_kernel(const float* __restrict__ scores,
                                                    int* __restrict__ pidx) {
    __shared__ float v[2048];
    __shared__ int   ix[2048];
    int b = blockIdx.x;
    int t = threadIdx.x;
    for (int i = t; i < 2048; i += 1024) { v[i] = scores[b * 2048 + i]; ix[i] = i; }
    __syncthreads();
    for (int k = 2; k <= 2048; k <<= 1) {
        for (int j = k >> 1; j > 0; j >>= 1) {
            for (int i = t; i < 2048; i += 1024) {
                int o = i ^ j;
                if (o > i) {
                    bool desc = ((i & k) == 0);
                    float va = v[i], vb = v[o];
                    int ia = ix[i], ib = ix[o];
                    bool b_first = (vb > va) || (vb == va && ib < ia);
                    if (desc == b_first) { v[i] = vb; v[o] = va; ix[i] = ib; ix[o] = ia; }
                }
            }
            __syncthreads();
        }
    }
    if (t < KSEL_) pidx[b * KSEL_ + t] = ix[t];
}

// ---------------------------------------------------------------------------
// gathers: id in [0,2048): selact[b][s][t] = C[b][s][pidx[b][t]]
//          id in [2048,2560): PselT[b][d][k] = bf16(proj[pidx[b][k]][d])
// base offsets blockIdx so the small-ws path can launch only the proj part.
// ---------------------------------------------------------------------------
__global__ __launch_bounds__(256) void gathers_kernel(
        const unsigned short* __restrict__ C, const float* __restrict__ proj,
        const int* __restrict__ pidx,
        unsigned short* __restrict__ selact, unsigned short* __restrict__ PselT,
        int base) {
    __shared__ int pj[256];
    __shared__ unsigned short tile[64][65];
    int id = blockIdx.x + base, t = threadIdx.x;
    if (id < 2048) {
        int b = id >> 8;
        pj[t] = pidx[b * KSEL_ + t];
        __syncthreads();
        size_t r0 = (size_t)b * S_ + (id & 255) * 8;
#pragma unroll
        for (int r = 0; r < 8; ++r) {
            size_t row = r0 + r;
            selact[row * KSEL_ + t] = C[row * P_ + pj[t]];
        }
    } else {
        int g = id - 2048;
        int d0 = (g & 15) * 64, k0 = ((g >> 4) & 3) * 64, b = g >> 6;
        int tr = t >> 6;     // 0..3
        int tc = t & 63;
#pragma unroll
        for (int r = 0; r < 16; r++) {
            int kk = r * 4 + tr;
            int prow = pidx[b * KSEL_ + k0 + kk];
            tile[kk][tc] = f2bf(proj[(size_t)prow * D_ + d0 + tc]);
        }
        __syncthreads();
#pragma unroll
        for (int r = 0; r < 16; r++) {
            int dd = r * 4 + tr;
            PselT[((size_t)(b * D_ + d0 + dd)) * KSEL_ + k0 + tc] = tile[tc][dd];
        }
    }
}

// ---------------------------------------------------------------------------
// gemm1b (fallback when ws too small): recompute selected 256 columns.
// Ahi/Ghi/Glo staged (single buffer); AloF direct.
// ---------------------------------------------------------------------------
__global__ __launch_bounds__(256) void gemm1b_selact(
        const unsigned short* __restrict__ Ahi, const unsigned short* __restrict__ AloF,
        const unsigned short* __restrict__ Ghi, const unsigned short* __restrict__ Glo,
        const int* __restrict__ pidx, unsigned short* __restrict__ selact) {
    __shared__ __align__(16) unsigned short lds[16384];

    const int t  = threadIdx.x;
    const int b  = blockIdx.z;
    const int s0 = blockIdx.y * 128;
    const int n0 = blockIdx.x * 128;
    const int w = t >> 6, l = t & 63;
    const int wm = w & 1, wn = w >> 1;
    const int lr = l & 15, quad = l >> 4;

    const int srow = t >> 2;
    const int koff = ((t & 3) ^ ((t >> 3) & 3)) * 8;
    const size_t baseA = ((size_t)(b * S_ + s0)) * KIN_;
    const size_t offA0 = baseA + (size_t)srow * KIN_ + koff;
    const size_t offA1 = offA0 + (size_t)64 * KIN_;
    const int prow0 = pidx[b * KSEL_ + n0 + srow];
    const int prow1 = pidx[b * KSEL_ + n0 + 64 + srow];
    const size_t offG0 = ((size_t)(b * P_ + prow0)) * KIN_ + koff;
    const size_t offG1 = ((size_t)(b * P_ + prow1)) * KIN_ + koff;
    const unsigned short* alB = AloF + (size_t)b * 1048576
                              + (size_t)((s0 >> 4) + wm * 4) * 512 + (size_t)l * 8;
    char* lb = (char*)lds + w * 1024;

    int ra[4], rg[4];
#pragma unroll
    for (int i = 0; i < 4; i++) {
        int rowa = wm * 64 + i * 16 + lr;
        int rowg = wn * 64 + i * 16 + lr;
        ra[i] = rowa * 32 + (quad ^ ((rowa >> 1) & 3)) * 8;
        rg[i] = rowg * 32 + (quad ^ ((rowg >> 1) & 3)) * 8;
    }

    f32x4 acc[4][4];
#pragma unroll
    for (int i = 0; i < 4; i++)
#pragma unroll
        for (int jj = 0; jj < 4; jj++) acc[i][jj] = (f32x4){0.f, 0.f, 0.f, 0.f};

    for (int k0 = 0; k0 < KIN_; k0 += 32) {
        int kb = k0 >> 5;
        gl2lds16(Ahi + offA0 + k0, lb + 0);
        gl2lds16(Ahi + offA1 + k0, lb + 4096);
        gl2lds16(Ghi + offG0 + k0, lb + 8192);
        gl2lds16(Ghi + offG1 + k0, lb + 12288);
        gl2lds16(Glo + offG0 + k0, lb + 16384);
        gl2lds16(Glo + offG1 + k0, lb + 20480);
        short8 alc[4];
#pragma unroll
        for (int i = 0; i < 4; i++)
            alc[i] = *(const short8*)(alB + (size_t)kb * 65536 + i * 512);
        __syncthreads();

        short8 gh[4], gl8[4];
#pragma unroll
        for (int i = 0; i < 4; i++) {
            gh[i]  = *(const short8*)(lds + 4096 + rg[i]);
            gl8[i] = *(const short8*)(lds + 8192 + rg[i]);
        }
#pragma unroll
        for (int mt = 0; mt < 4; mt++) {
            short8 ah = *(const short8*)(lds + ra[mt]);
#pragma unroll
            for (int nt = 0; nt < 4; nt++) {
                acc[mt][nt] = __builtin_amdgcn_mfma_f32_16x16x32_bf16(ah,      gh[nt],  acc[mt][nt], 0, 0, 0);
                acc[mt][nt] = __builtin_amdgcn_mfma_f32_16x16x32_bf16(ah,      gl8[nt], acc[mt][nt], 0, 0, 0);
                acc[mt][nt] = __builtin_amdgcn_mfma_f32_16x16x32_bf16(alc[mt], gh[nt],  acc[mt][nt], 0, 0, 0);
            }
        }
        __syncthreads();
    }

#pragma unroll
    for (int mt = 0; mt < 4; mt++)
#pragma unroll
        for (int nt = 0; nt < 4; nt++)
#pragma unroll
            for (int r = 0; r < 4; r++) {
                int row = wm * 64 + mt * 16 + quad * 4 + r;
                int col = wn * 64 + nt * 16 + lr;
                lds[row * 128 + col] = f2bf(gelu_exact(acc[mt][nt][r]));
            }
    __syncthreads();
    for (int i = t; i < 2048; i += 256) {
        int row = i >> 4, ch = i & 15;
        uint4 v = *(const uint4*)(lds + row * 128 + ch * 8);
        *(uint4*)(selact + ((size_t)(b * S_ + s0 + row)) * KSEL_ + n0 + ch * 8) = v;
    }
}

// ---------------------------------------------------------------------------
// gemm2: out[b][s][d] = sum_k selact[b][s][k] * PselT[b][d][k]  (bf16 MFMA)
// dbuf LDS + raw vmcnt(4)/s_barrier pipeline; XOR source+read swizzle.
// ---------------------------------------------------------------------------
__global__ __launch_bounds__(256) void gemm2_mfma(
        const unsigned short* __restrict__ selact,
        const unsigned short* __restrict__ PselT,
        float* __restrict__ out) {
    __shared__ __align__(16) unsigned short lds[16384];  // 2 x 16KB buffers

    const int t  = threadIdx.x;
    const int b  = blockIdx.z;
    const int s0 = blockIdx.y * 128;
    const int d0 = blockIdx.x * 128;
    const int w = t >> 6, l = t & 63;
    const int wm = w & 1, wn = w >> 1;
    const int lr = l & 15, quad = l >> 4;

    const int srow = t >> 2;
    const int koff = ((t & 3) ^ ((t >> 3) & 3)) * 8;
    const unsigned short* pA0 = selact + ((size_t)(b * S_ + s0 + srow)) * KSEL_ + koff;
    const unsigned short* pA1 = pA0 + (size_t)64 * KSEL_;
    const unsigned short* pB0 = PselT + ((size_t)(b * D_ + d0 + srow)) * KSEL_ + koff;
    const unsigned short* pB1 = pB0 + (size_t)64 * KSEL_;
    char* lb = (char*)lds + w * 1024;

    int ra[4], rg[4];
#pragma unroll
    for (int i = 0; i < 4; i++) {
        int rowa = wm * 64 + i * 16 + lr;
        int rowg = wn * 64 + i * 16 + lr;
        ra[i] = rowa * 32 + (quad ^ ((rowa >> 1) & 3)) * 8;
        rg[i] = rowg * 32 + (quad ^ ((rowg >> 1) & 3)) * 8;
    }

    f32x4 acc[4][4];
#pragma unroll
    for (int i = 0; i < 4; i++)
#pragma unroll
        for (int jj = 0; jj < 4; jj++) acc[i][jj] = (f32x4){0.f, 0.f, 0.f, 0.f};

    auto issue = [&](int k0, int buf) {
        char* dst = lb + buf * 16384;
        gl2lds16(pA0 + k0, dst + 0);
        gl2lds16(pA1 + k0, dst + 4096);
        gl2lds16(pB0 + k0, dst + 8192);
        gl2lds16(pB1 + k0, dst + 12288);
    };

    issue(0, 0);
    for (int it = 0; it < KSEL_ / 32; ++it) {
        if (it + 1 < KSEL_ / 32) {
            issue((it + 1) * 32, (it + 1) & 1);
            asm volatile("s_waitcnt vmcnt(4)\n\ts_barrier" ::: "memory");
        } else {
            asm volatile("s_waitcnt vmcnt(0)\n\ts_barrier" ::: "memory");
        }
        const unsigned short* Lb = lds + (it & 1) * 8192;

        short8 af[4], bf[4];
#pragma unroll
        for (int i = 0; i < 4; i++) {
            af[i] = *(const short8*)(Lb + ra[i]);
            bf[i] = *(const short8*)(Lb + 4096 + rg[i]);
        }
#pragma unroll
        for (int mt = 0; mt < 4; mt++)
#pragma unroll
            for (int nt = 0; nt < 4; nt++)
                acc[mt][nt] = __builtin_amdgcn_mfma_f32_16x16x32_bf16(af[mt], bf[nt], acc[mt][nt], 0, 0, 0);
        asm volatile("s_barrier" ::: "memory");
    }

#pragma unroll
    for (int mt = 0; mt < 4; mt++)
#pragma unroll
        for (int nt = 0; nt < 4; nt++)
#pragma unroll
            for (int r = 0; r < 4; r++)
                out[((size_t)(b * S_ + s0 + wm * 64 + mt * 16 + quad * 4 + r)) * D_
                    + d0 + wn * 64 + nt * 16 + lr] = acc[mt][nt][r];
}

// ---------------------------------------------------------------------------
// Workspace layout (bytes):
//   Ahi/AloF/Ghi/Glo bf16 @ 0..67108863   (4 x 16,777,216; AloF frag-swizzled)
//   scores fp32           @ 67,108,864    (65,536)
//   pidx   int            @ 67,174,400    (8,192)
//   selact bf16           @ 67,182,592    (8,388,608)
//   PselT  bf16           @ 75,571,200    (4,194,304)      -> 79,765,504 (base)
//   C      bf16 [8][2048][2048] @ 79,765,504 (67,108,864)  -> 146,874,368 (big)
// ---------------------------------------------------------------------------
extern "C" void kernel_launch(void* const* d_in, const int* in_sizes, int n_in,
                              void* d_out, int out_size, void* d_ws, size_t ws_size,
                              hipStream_t stream) {
    (void)in_sizes; (void)n_in; (void)out_size;
    const float* act  = (const float*)d_in[0];
    const int*   idx  = (const int*)d_in[1];
    const float* W    = (const float*)d_in[3];
    const float* proj = (const float*)d_in[4];
    float*       out  = (float*)d_out;

    char* ws = (char*)d_ws;
    unsigned short* Ahi    = (unsigned short*)(ws + 0);
    unsigned short* AloF   = (unsigned short*)(ws + 16777216);
    unsigned short* Ghi    = (unsigned short*)(ws + 33554432);
    unsigned short* Glo    = (unsigned short*)(ws + 50331648);
    float*          scores = (float*)(ws + 67108864);
    int*            pidx   = (int*)(ws + 67174400);
    unsigned short* selact = (unsigned short*)(ws + 67182592);
    unsigned short* PselT  = (unsigned short*)(ws + 75571200);
    unsigned short* Cbf    = (unsigned short*)(ws + 79765504);
    const bool big = ws_size >= 146874368ull;

    hipMemsetAsync(scores, 0, B_ * P_ * sizeof(float), stream);

    prep_kernel<<<dim3(1024 + (B_ * P_) / 4), 256, 0, stream>>>(act, W, idx, Ahi, AloF, Ghi, Glo);

    if (big) {
        gemm1_score<true><<<dim3(2048), 256, 0, stream>>>(Ahi, AloF, Ghi, Glo, scores, Cbf);
        topk_kernel<<<dim3(B_), 1024, 0, stream>>>(scores, pidx);
        gathers_kernel<<<dim3(2048 + 512), 256, 0, stream>>>(Cbf, proj, pidx, selact, PselT, 0);
    } else {
        gemm1_score<false><<<dim3(2048), 256, 0, stream>>>(Ahi, AloF, Ghi, Glo, scores, nullptr);
        topk_kernel<<<dim3(B_), 1024, 0, stream>>>(scores, pidx);
        gemm1b_selact<<<dim3(KSEL_ / 128, S_ / 128, B_), 256, 0, stream>>>(
            Ahi, AloF, Ghi, Glo, pidx, selact);
        gathers_kernel<<<dim3(512), 256, 0, stream>>>(Cbf, proj, pidx, selact, PselT, 2048);
    }
    gemm2_mfma<<<dim3(D_ / 128, S_ / 128, B_), 256, 0, stream>>>(selact, PselT, out);
}

// Round 5
// 355.567 us; speedup vs baseline: 1.1161x; 1.0029x over previous
//
#include <hip/hip_runtime.h>
#include <hip/hip_bf16.h>
#include <math.h>

#define B_    8
#define S_    2048
#define KIN_  512
#define NIN_  4096
#define P_    2048
#define D_    1024
#define KSEL_ 256

typedef __attribute__((ext_vector_type(8))) short short8;
typedef __attribute__((ext_vector_type(4))) float f32x4;

__device__ __forceinline__ unsigned short f2bf(float f) {
    unsigned u = __float_as_uint(f);
    unsigned r = (u + 0x7fffu + ((u >> 16) & 1u)) >> 16;
    return (unsigned short)r;
}
__device__ __forceinline__ float bf2f(unsigned short h) {
    return __uint_as_float(((unsigned)h) << 16);
}
__device__ __forceinline__ float gelu_exact(float x) {
    return 0.5f * x * (1.0f + erff(x * 0.70710678118654752f));
}
__device__ __forceinline__ void gl2lds16(const void* g, void* l) {
    __builtin_amdgcn_global_load_lds(
        (const __attribute__((address_space(1))) unsigned int*)g,
        (__attribute__((address_space(3))) unsigned int*)l, 16, 0, 0);
}

// ---------------------------------------------------------------------------
// AloF fragment-swizzled layout (16 MB):
//   AloF[b][kb][sb][lane][8]: element (s,k) at b*1048576 + (k>>5)*65536
//       + (s>>4)*512 + (((k>>3)&3)*16 + (s&15))*8 + (k&7)
// A 16-row x 32-k MFMA fragment block is a contiguous 1KB chunk -> one
// coalesced global_load_dwordx4 per lane, straight into the MFMA operand.
// Ghi/Glo stay row-major (staged via global_load_lds in gemm1).
// ---------------------------------------------------------------------------

// ---------------------------------------------------------------------------
// prep: blocks [0,1024): split A fp32 -> Ahi (row-major bf16) + AloF
//       blocks [1024,3072): one W row per block. Stage the 16KB row in LDS
//       (coalesced float4) + all 8 batches' idx (16KB); each wave gathers
//       from LDS and writes 2 batches' (Ghi,Glo) rows. Global gather reads
//       drop 8x vs per-(b,p) gathering (W read once, coalesced).
// ---------------------------------------------------------------------------
__global__ __launch_bounds__(256) void prep_kernel(
        const float* __restrict__ A, const float* __restrict__ W,
        const int* __restrict__ idx,
        unsigned short* __restrict__ Ahi, unsigned short* __restrict__ AloF,
        unsigned short* __restrict__ Ghi, unsigned short* __restrict__ Glo) {
    __shared__ float wrow_s[NIN_];      // 16KB
    __shared__ int   ibs8[B_ * KIN_];   // 16KB
    int id = blockIdx.x;
    int t  = threadIdx.x;
    if (id < 1024) {
        int b = id >> 7, rb = id & 127;
        int l = t & 63, wv = t >> 6;
        int lr = l & 15, quad = l >> 4;
        const float* src = A + ((size_t)(b * S_ + rb * 16 + lr)) * KIN_ + quad * 8;
        unsigned short* dh = Ahi + ((size_t)(b * S_ + rb * 16 + lr)) * KIN_ + quad * 8;
        unsigned short* dl = AloF + (size_t)b * 1048576 + (size_t)rb * 512 + (size_t)l * 8;
        for (int kb = wv; kb < 16; kb += 4) {
            float4 v0 = *(const float4*)(src + kb * 32);
            float4 v1 = *(const float4*)(src + kb * 32 + 4);
            float vv[8] = {v0.x, v0.y, v0.z, v0.w, v1.x, v1.y, v1.z, v1.w};
            short8 h8, l8;
#pragma unroll
            for (int jj = 0; jj < 8; jj++) {
                unsigned short h = f2bf(vv[jj]);
                h8[jj] = (short)h;
                l8[jj] = (short)f2bf(vv[jj] - bf2f(h));
            }
            *(short8*)(dh + kb * 32) = h8;
            *(short8*)(dl + (size_t)kb * 65536) = l8;
        }
    } else {
        int p = id - 1024;              // 0..2047: one W row, all 8 batches
        const float* wrow = W + (size_t)p * NIN_;
#pragma unroll
        for (int i = 0; i < 4; i++)     // 4096 floats = 1024 float4
            *(float4*)(wrow_s + (t + i * 256) * 4) =
                *(const float4*)(wrow + (t + i * 256) * 4);
#pragma unroll
        for (int i = 0; i < 16; i++)    // 8*512 ints, idx is b-major flat
            ibs8[t + i * 256] = idx[t + i * 256];
        __syncthreads();
        int wv = t >> 6, tt = t & 63;
#pragma unroll
        for (int bi = 0; bi < 2; ++bi) {
            int b = wv * 2 + bi;
            size_t o = ((size_t)b * P_ + p) * KIN_;
            const int* ib = ibs8 + b * KIN_;
            short8 h8, l8;
#pragma unroll
            for (int e = 0; e < 8; e++) {
                float v = wrow_s[ib[tt * 8 + e]];
                unsigned short h = f2bf(v);
                h8[e] = (short)h;
                l8[e] = (short)f2bf(v - bf2f(h));
            }
            *(short8*)(Ghi + o + tt * 8) = h8;
            *(short8*)(Glo + o + tt * 8) = l8;
        }
    }
}

// ---------------------------------------------------------------------------
// gemm1_score: x = A*G^T (3-term split bf16 MFMA), scores += sum_s gelu(x).
// Optionally (STORE_C) writes bf16 gelu(x) to C [b][s][p].
// 128x128 tile, BK=32. LDS stages Ahi/Ghi/Glo (2 x 24KB dbuf -> 48KB,
// 3 blocks/CU with ~148 total regs); AloF fragments loaded direct
// global->reg (coalesced, L2-hot). Source+read XOR swizzle kills the
// ds_read_b128 bank conflicts; epilogue tile padded to 136-short rows.
// vmcnt(10) = 6 staging(it) drained; 4 alc + 6 staging(it+1) in flight.
// Block swizzle: 4x4 (p,s)-tile clusters pinned to one XCD.
// NOTE (R2 lesson): do NOT raise min-waves to 4 — the unified VGPR file
// gives only 64 arch VGPRs at 128 total, starving the direct-load pipeline.
// ---------------------------------------------------------------------------
template <bool STORE_C>
__global__ __launch_bounds__(256, 3) void gemm1_score(
        const unsigned short* __restrict__ Ahi, const unsigned short* __restrict__ AloF,
        const unsigned short* __restrict__ Ghi, const unsigned short* __restrict__ Glo,
        float* __restrict__ scores, unsigned short* __restrict__ C) {
    __shared__ __align__(16) unsigned short lds[24576];  // 2 x 24KB buffers

    // --- XCD cluster swizzle ---
    int d    = blockIdx.x;             // 0..2047
    int xcd  = d & 7;
    int slot = d >> 3;                 // 0..255
    int c    = (slot >> 4) * 8 + xcd;  // cluster 0..127
    int j    = slot & 15;              // position in 4x4 cluster
    int b    = c >> 4;
    int rc   = c & 15;
    int p0   = ((rc & 3) * 4 + (j & 3)) * 128;
    int s0   = ((rc >> 2) * 4 + (j >> 2)) * 128;

    const int t  = threadIdx.x;
    const int w = t >> 6, l = t & 63;
    const int wm = w & 1, wn = w >> 1;
    const int lr = l & 15, quad = l >> 4;

    const int srow = t >> 2;
    const int koff = ((t & 3) ^ ((t >> 3) & 3)) * 8;   // source-side swizzle
    const size_t baseA = ((size_t)(b * S_ + s0)) * KIN_;
    const size_t baseG = ((size_t)(b * P_ + p0)) * KIN_;
    const unsigned short* pA0 = Ahi + baseA + (size_t)srow * KIN_ + koff;
    const unsigned short* pA1 = pA0 + (size_t)64 * KIN_;
    const unsigned short* pG0 = Ghi + baseG + (size_t)srow * KIN_ + koff;
    const unsigned short* pG1 = pG0 + (size_t)64 * KIN_;
    const unsigned short* pH0 = Glo + baseG + (size_t)srow * KIN_ + koff;
    const unsigned short* pH1 = pH0 + (size_t)64 * KIN_;
    const unsigned short* alB = AloF + (size_t)b * 1048576
                              + (size_t)((s0 >> 4) + wm * 4) * 512 + (size_t)l * 8;
    char* lb = (char*)lds + w * 1024;

    int ra[4], rg[4];
#pragma unroll
    for (int i = 0; i < 4; i++) {
        int rowa = wm * 64 + i * 16 + lr;
        int rowg = wn * 64 + i * 16 + lr;
        ra[i] = rowa * 32 + (quad ^ ((rowa >> 1) & 3)) * 8;
        rg[i] = rowg * 32 + (quad ^ ((rowg >> 1) & 3)) * 8;
    }

    f32x4 acc[4][4];
#pragma unroll
    for (int i = 0; i < 4; i++)
#pragma unroll
        for (int jj = 0; jj < 4; jj++) acc[i][jj] = (f32x4){0.f, 0.f, 0.f, 0.f};

    auto issue = [&](int k0, int buf) {
        char* dst = lb + buf * 24576;
        gl2lds16(pA0 + k0, dst + 0);
        gl2lds16(pA1 + k0, dst + 4096);
        gl2lds16(pG0 + k0, dst + 8192);
        gl2lds16(pG1 + k0, dst + 12288);
        gl2lds16(pH0 + k0, dst + 16384);
        gl2lds16(pH1 + k0, dst + 20480);
    };

    issue(0, 0);
    for (int it = 0; it < KIN_ / 32; ++it) {
        // Alo fragments for this K-step, direct from global (coalesced 1KB).
        short8 alc[4];
#pragma unroll
        for (int mt = 0; mt < 4; mt++)
            alc[mt] = *(const short8*)(alB + (size_t)it * 65536 + mt * 512);
        if (it + 1 < KIN_ / 32) {
            issue((it + 1) * 32, (it + 1) & 1);
            // outstanding: staging(it)[6] + alc(it)[4] + staging(it+1)[6]
            asm volatile("s_waitcnt vmcnt(10)\n\ts_barrier" ::: "memory");
        } else {
            asm volatile("s_waitcnt vmcnt(0)\n\ts_barrier" ::: "memory");
        }
        const unsigned short* Lb = lds + (it & 1) * 12288;

        short8 gh[4], gl8[4];
#pragma unroll
        for (int i = 0; i < 4; i++) {
            gh[i]  = *(const short8*)(Lb + 4096 + rg[i]);
            gl8[i] = *(const short8*)(Lb + 8192 + rg[i]);
        }
#pragma unroll
        for (int mt = 0; mt < 4; mt++) {
            short8 ah = *(const short8*)(Lb + ra[mt]);
#pragma unroll
            for (int nt = 0; nt < 4; nt++) {
                acc[mt][nt] = __builtin_amdgcn_mfma_f32_16x16x32_bf16(ah,      gh[nt],  acc[mt][nt], 0, 0, 0);
                acc[mt][nt] = __builtin_amdgcn_mfma_f32_16x16x32_bf16(ah,      gl8[nt], acc[mt][nt], 0, 0, 0);
                acc[mt][nt] = __builtin_amdgcn_mfma_f32_16x16x32_bf16(alc[mt], gh[nt],  acc[mt][nt], 0, 0, 0);
            }
        }
        asm volatile("s_barrier" ::: "memory");
    }

    // Epilogue: gelu, per-column score sums, optional bf16 C tile store
    float colsum[4] = {0.f, 0.f, 0.f, 0.f};
#pragma unroll
    for (int mt = 0; mt < 4; mt++)
#pragma unroll
        for (int nt = 0; nt < 4; nt++)
#pragma unroll
            for (int r = 0; r < 4; r++) {
                float g = gelu_exact(acc[mt][nt][r]);
                colsum[nt] += g;
                acc[mt][nt][r] = g;
            }
#pragma unroll
    for (int nt = 0; nt < 4; nt++) {
        colsum[nt] += __shfl_xor(colsum[nt], 16);
        colsum[nt] += __shfl_xor(colsum[nt], 32);
    }
    if (quad == 0) {
#pragma unroll
        for (int nt = 0; nt < 4; nt++)
            atomicAdd(&scores[b * P_ + p0 + wn * 64 + nt * 16 + lr], colsum[nt]);
    }

    if (STORE_C) {
        // padded tile: 136-short rows (272B, 16B-aligned) -> banks spread
#pragma unroll
        for (int mt = 0; mt < 4; mt++)
#pragma unroll
            for (int nt = 0; nt < 4; nt++)
#pragma unroll
                for (int r = 0; r < 4; r++) {
                    int row = wm * 64 + mt * 16 + quad * 4 + r;
                    int col = wn * 64 + nt * 16 + lr;
                    lds[row * 136 + col] = f2bf(acc[mt][nt][r]);
                }
        __syncthreads();
        for (int i = t; i < 2048; i += 256) {
            int row = i >> 4, ch = i & 15;
            uint4 v = *(const uint4*)(lds + row * 136 + ch * 8);
            *(uint4*)(C + ((size_t)(b * S_ + s0 + row)) * P_ + p0 + ch * 8) = v;
        }
    }
}

// ---------------------------------------------------------------------------
// top-256 of 2048 scores per batch (bitonic, desc, tie: low idx).
// After selection, the 256 chosen indices are re-sorted ASCENDING: the
// output einsum is invariant under permutation of k (selact and PselT use
// the same pidx order), and ascending indices make the downstream C-column
// and proj-row gathers near-sequential.
// ---------------------------------------------------------------------------
__global__ __launch_bounds__(1024) void topk_kernel(const float* __restrict__ scores,
                                                    int* __restrict__ pidx) {
    __shared__ float v[2048];
    __shared__ int   ix[2048];
    int b = blockIdx.x;
    int t = threadIdx.x;
    for (int i = t; i < 2048; i += 1024) { v[i] = scores[b * 2048 + i]; ix[i] = i; }
    __syncthreads();
    for (int k = 2; k <= 2048; k <<= 1) {
        for (int j = k >> 1; j > 0; j >>= 1) {
            for (int i = t; i < 2048; i += 1024) {
                int o = i ^ j;
                if (o > i) {
                    bool desc = ((i & k) == 0);
                    float va = v[i], vb = v[o];
                    int ia = ix[i], ib = ix[o];
                    bool b_first = (vb > va) || (vb == va && ib < ia);
                    if (desc == b_first) { v[i] = vb; v[o] = va; ix[i] = ib; ix[o] = ia; }
                }
            }
            __syncthreads();
        }
    }
    // ascending re-sort of the selected 256 indices (set-invariant)
    for (int k = 2; k <= 256; k <<= 1) {
        for (int j = k >> 1; j > 0; j >>= 1) {
            if (t < 256) {
                int i = t, o = i ^ j;
                if (o > i) {
                    bool asc = ((i & k) == 0);
                    int a = ix[i], c2 = ix[o];
                    if ((a > c2) == asc) { ix[i] = c2; ix[o] = a; }
                }
            }
            __syncthreads();
        }
    }
    if (t < KSEL_) pidx[b * KSEL_ + t] = ix[t];
}

// ---------------------------------------------------------------------------
// gathers: id in [0,2048): selact[b][s][t] = C[b][s][pidx[b][t]]
//          id in [2048,2560): PselT[b][d][k] = bf16(proj[pidx[b][k]][d])
// base offsets blockIdx so the small-ws path can launch only the proj part.
// ---------------------------------------------------------------------------
__global__ __launch_bounds__(256) void gathers_kernel(
        const unsigned short* __restrict__ C, const float* __restrict__ proj,
        const int* __restrict__ pidx,
        unsigned short* __restrict__ selact, unsigned short* __restrict__ PselT,
        int base) {
    __shared__ int pj[256];
    __shared__ unsigned short tile[64][65];
    int id = blockIdx.x + base, t = threadIdx.x;
    if (id < 2048) {
        int b = id >> 8;
        pj[t] = pidx[b * KSEL_ + t];
        __syncthreads();
        size_t r0 = (size_t)b * S_ + (id & 255) * 8;
#pragma unroll
        for (int r = 0; r < 8; ++r) {
            size_t row = r0 + r;
            selact[row * KSEL_ + t] = C[row * P_ + pj[t]];
        }
    } else {
        int g = id - 2048;
        int d0 = (g & 15) * 64, k0 = ((g >> 4) & 3) * 64, b = g >> 6;
        int tr = t >> 6;     // 0..3
        int tc = t & 63;
#pragma unroll
        for (int r = 0; r < 16; r++) {
            int kk = r * 4 + tr;
            int prow = pidx[b * KSEL_ + k0 + kk];
            tile[kk][tc] = f2bf(proj[(size_t)prow * D_ + d0 + tc]);
        }
        __syncthreads();
#pragma unroll
        for (int r = 0; r < 16; r++) {
            int dd = r * 4 + tr;
            PselT[((size_t)(b * D_ + d0 + dd)) * KSEL_ + k0 + tc] = tile[tc][dd];
        }
    }
}

// ---------------------------------------------------------------------------
// gemm1b (fallback when ws too small): recompute selected 256 columns.
// Ahi/Ghi/Glo staged (single buffer); AloF direct.
// ---------------------------------------------------------------------------
__global__ __launch_bounds__(256) void gemm1b_selact(
        const unsigned short* __restrict__ Ahi, const unsigned short* __restrict__ AloF,
        const unsigned short* __restrict__ Ghi, const unsigned short* __restrict__ Glo,
        const int* __restrict__ pidx, unsigned short* __restrict__ selact) {
    __shared__ __align__(16) unsigned short lds[16384];

    const int t  = threadIdx.x;
    const int b  = blockIdx.z;
    const int s0 = blockIdx.y * 128;
    const int n0 = blockIdx.x * 128;
    const int w = t >> 6, l = t & 63;
    const int wm = w & 1, wn = w >> 1;
    const int lr = l & 15, quad = l >> 4;

    const int srow = t >> 2;
    const int koff = ((t & 3) ^ ((t >> 3) & 3)) * 8;
    const size_t baseA = ((size_t)(b * S_ + s0)) * KIN_;
    const size_t offA0 = baseA + (size_t)srow * KIN_ + koff;
    const size_t offA1 = offA0 + (size_t)64 * KIN_;
    const int prow0 = pidx[b * KSEL_ + n0 + srow];
    const int prow1 = pidx[b * KSEL_ + n0 + 64 + srow];
    const size_t offG0 = ((size_t)(b * P_ + prow0)) * KIN_ + koff;
    const size_t offG1 = ((size_t)(b * P_ + prow1)) * KIN_ + koff;
    const unsigned short* alB = AloF + (size_t)b * 1048576
                              + (size_t)((s0 >> 4) + wm * 4) * 512 + (size_t)l * 8;
    char* lb = (char*)lds + w * 1024;

    int ra[4], rg[4];
#pragma unroll
    for (int i = 0; i < 4; i++) {
        int rowa = wm * 64 + i * 16 + lr;
        int rowg = wn * 64 + i * 16 + lr;
        ra[i] = rowa * 32 + (quad ^ ((rowa >> 1) & 3)) * 8;
        rg[i] = rowg * 32 + (quad ^ ((rowg >> 1) & 3)) * 8;
    }

    f32x4 acc[4][4];
#pragma unroll
    for (int i = 0; i < 4; i++)
#pragma unroll
        for (int jj = 0; jj < 4; jj++) acc[i][jj] = (f32x4){0.f, 0.f, 0.f, 0.f};

    for (int k0 = 0; k0 < KIN_; k0 += 32) {
        int kb = k0 >> 5;
        gl2lds16(Ahi + offA0 + k0, lb + 0);
        gl2lds16(Ahi + offA1 + k0, lb + 4096);
        gl2lds16(Ghi + offG0 + k0, lb + 8192);
        gl2lds16(Ghi + offG1 + k0, lb + 12288);
        gl2lds16(Glo + offG0 + k0, lb + 16384);
        gl2lds16(Glo + offG1 + k0, lb + 20480);
        short8 alc[4];
#pragma unroll
        for (int i = 0; i < 4; i++)
            alc[i] = *(const short8*)(alB + (size_t)kb * 65536 + i * 512);
        __syncthreads();

        short8 gh[4], gl8[4];
#pragma unroll
        for (int i = 0; i < 4; i++) {
            gh[i]  = *(const short8*)(lds + 4096 + rg[i]);
            gl8[i] = *(const short8*)(lds + 8192 + rg[i]);
        }
#pragma unroll
        for (int mt = 0; mt < 4; mt++) {
            short8 ah = *(const short8*)(lds + ra[mt]);
#pragma unroll
            for (int nt = 0; nt < 4; nt++) {
                acc[mt][nt] = __builtin_amdgcn_mfma_f32_16x16x32_bf16(ah,      gh[nt],  acc[mt][nt], 0, 0, 0);
                acc[mt][nt] = __builtin_amdgcn_mfma_f32_16x16x32_bf16(ah,      gl8[nt], acc[mt][nt], 0, 0, 0);
                acc[mt][nt] = __builtin_amdgcn_mfma_f32_16x16x32_bf16(alc[mt], gh[nt],  acc[mt][nt], 0, 0, 0);
            }
        }
        __syncthreads();
    }

#pragma unroll
    for (int mt = 0; mt < 4; mt++)
#pragma unroll
        for (int nt = 0; nt < 4; nt++)
#pragma unroll
            for (int r = 0; r < 4; r++) {
                int row = wm * 64 + mt * 16 + quad * 4 + r;
                int col = wn * 64 + nt * 16 + lr;
                lds[row * 128 + col] = f2bf(gelu_exact(acc[mt][nt][r]));
            }
    __syncthreads();
    for (int i = t; i < 2048; i += 256) {
        int row = i >> 4, ch = i & 15;
        uint4 v = *(const uint4*)(lds + row * 128 + ch * 8);
        *(uint4*)(selact + ((size_t)(b * S_ + s0 + row)) * KSEL_ + n0 + ch * 8) = v;
    }
}

// ---------------------------------------------------------------------------
// gemm2: out[b][s][d] = sum_k selact[b][s][k] * PselT[b][d][k]  (bf16 MFMA)
// dbuf LDS + raw vmcnt(4)/s_barrier pipeline; XOR source+read swizzle.
// ---------------------------------------------------------------------------
__global__ __launch_bounds__(256) void gemm2_mfma(
        const unsigned short* __restrict__ selact,
        const unsigned short* __restrict__ PselT,
        float* __restrict__ out) {
    __shared__ __align__(16) unsigned short lds[16384];  // 2 x 16KB buffers

    const int t  = threadIdx.x;
    const int b  = blockIdx.z;
    const int s0 = blockIdx.y * 128;
    const int d0 = blockIdx.x * 128;
    const int w = t >> 6, l = t & 63;
    const int wm = w & 1, wn = w >> 1;
    const int lr = l & 15, quad = l >> 4;

    const int srow = t >> 2;
    const int koff = ((t & 3) ^ ((t >> 3) & 3)) * 8;
    const unsigned short* pA0 = selact + ((size_t)(b * S_ + s0 + srow)) * KSEL_ + koff;
    const unsigned short* pA1 = pA0 + (size_t)64 * KSEL_;
    const unsigned short* pB0 = PselT + ((size_t)(b * D_ + d0 + srow)) * KSEL_ + koff;
    const unsigned short* pB1 = pB0 + (size_t)64 * KSEL_;
    char* lb = (char*)lds + w * 1024;

    int ra[4], rg[4];
#pragma unroll
    for (int i = 0; i < 4; i++) {
        int rowa = wm * 64 + i * 16 + lr;
        int rowg = wn * 64 + i * 16 + lr;
        ra[i] = rowa * 32 + (quad ^ ((rowa >> 1) & 3)) * 8;
        rg[i] = rowg * 32 + (quad ^ ((rowg >> 1) & 3)) * 8;
    }

    f32x4 acc[4][4];
#pragma unroll
    for (int i = 0; i < 4; i++)
#pragma unroll
        for (int jj = 0; jj < 4; jj++) acc[i][jj] = (f32x4){0.f, 0.f, 0.f, 0.f};

    auto issue = [&](int k0, int buf) {
        char* dst = lb + buf * 16384;
        gl2lds16(pA0 + k0, dst + 0);
        gl2lds16(pA1 + k0, dst + 4096);
        gl2lds16(pB0 + k0, dst + 8192);
        gl2lds16(pB1 + k0, dst + 12288);
    };

    issue(0, 0);
    for (int it = 0; it < KSEL_ / 32; ++it) {
        if (it + 1 < KSEL_ / 32) {
            issue((it + 1) * 32, (it + 1) & 1);
            asm volatile("s_waitcnt vmcnt(4)\n\ts_barrier" ::: "memory");
        } else {
            asm volatile("s_waitcnt vmcnt(0)\n\ts_barrier" ::: "memory");
        }
        const unsigned short* Lb = lds + (it & 1) * 8192;

        short8 af[4], bf[4];
#pragma unroll
        for (int i = 0; i < 4; i++) {
            af[i] = *(const short8*)(Lb + ra[i]);
            bf[i] = *(const short8*)(Lb + 4096 + rg[i]);
        }
#pragma unroll
        for (int mt = 0; mt < 4; mt++)
#pragma unroll
            for (int nt = 0; nt < 4; nt++)
                acc[mt][nt] = __builtin_amdgcn_mfma_f32_16x16x32_bf16(af[mt], bf[nt], acc[mt][nt], 0, 0, 0);
        asm volatile("s_barrier" ::: "memory");
    }

#pragma unroll
    for (int mt = 0; mt < 4; mt++)
#pragma unroll
        for (int nt = 0; nt < 4; nt++)
#pragma unroll
            for (int r = 0; r < 4; r++)
                out[((size_t)(b * S_ + s0 + wm * 64 + mt * 16 + quad * 4 + r)) * D_
                    + d0 + wn * 64 + nt * 16 + lr] = acc[mt][nt][r];
}

// ---------------------------------------------------------------------------
// Workspace layout (bytes):
//   Ahi/AloF/Ghi/Glo bf16 @ 0..67108863   (4 x 16,777,216; AloF frag-swizzled)
//   scores fp32           @ 67,108,864    (65,536)
//   pidx   int            @ 67,174,400    (8,192)
//   selact bf16           @ 67,182,592    (8,388,608)
//   PselT  bf16           @ 75,571,200    (4,194,304)      -> 79,765,504 (base)
//   C      bf16 [8][2048][2048] @ 79,765,504 (67,108,864)  -> 146,874,368 (big)
// ---------------------------------------------------------------------------
extern "C" void kernel_launch(void* const* d_in, const int* in_sizes, int n_in,
                              void* d_out, int out_size, void* d_ws, size_t ws_size,
                              hipStream_t stream) {
    (void)in_sizes; (void)n_in; (void)out_size;
    const float* act  = (const float*)d_in[0];
    const int*   idx  = (const int*)d_in[1];
    const float* W    = (const float*)d_in[3];
    const float* proj = (const float*)d_in[4];
    float*       out  = (float*)d_out;

    char* ws = (char*)d_ws;
    unsigned short* Ahi    = (unsigned short*)(ws + 0);
    unsigned short* AloF   = (unsigned short*)(ws + 16777216);
    unsigned short* Ghi    = (unsigned short*)(ws + 33554432);
    unsigned short* Glo    = (unsigned short*)(ws + 50331648);
    float*          scores = (float*)(ws + 67108864);
    int*            pidx   = (int*)(ws + 67174400);
    unsigned short* selact = (unsigned short*)(ws + 67182592);
    unsigned short* PselT  = (unsigned short*)(ws + 75571200);
    unsigned short* Cbf    = (unsigned short*)(ws + 79765504);
    const bool big = ws_size >= 146874368ull;

    hipMemsetAsync(scores, 0, B_ * P_ * sizeof(float), stream);

    prep_kernel<<<dim3(1024 + P_), 256, 0, stream>>>(act, W, idx, Ahi, AloF, Ghi, Glo);

    if (big) {
        gemm1_score<true><<<dim3(2048), 256, 0, stream>>>(Ahi, AloF, Ghi, Glo, scores, Cbf);
        topk_kernel<<<dim3(B_), 1024, 0, stream>>>(scores, pidx);
        gathers_kernel<<<dim3(2048 + 512), 256, 0, stream>>>(Cbf, proj, pidx, selact, PselT, 0);
    } else {
        gemm1_score<false><<<dim3(2048), 256, 0, stream>>>(Ahi, AloF, Ghi, Glo, scores, nullptr);
        topk_kernel<<<dim3(B_), 1024, 0, stream>>>(scores, pidx);
        gemm1b_selact<<<dim3(KSEL_ / 128, S_ / 128, B_), 256, 0, stream>>>(
            Ahi, AloF, Ghi, Glo, pidx, selact);
        gathers_kernel<<<dim3(512), 256, 0, stream>>>(Cbf, proj, pidx, selact, PselT, 2048);
    }
    gemm2_mfma<<<dim3(D_ / 128, S_ / 128, B_), 256, 0, stream>>>(selact, PselT, out);
}